// Round 12
// baseline (145.182 us; speedup 1.0000x reference)
//
#include <hip/hip_runtime.h>

#define LATENT 128
#define HIDDEN 256
#define OUTD   128
#define TT     100
#define DECH   64
#define NMACRO 5    // RK4 macro-steps of 20 grid intervals (last = 19)

typedef _Float16 f16x8 __attribute__((ext_vector_type(8)));
typedef float    f32x4 __attribute__((ext_vector_type(4)));

#define MFMA16(a,b,c) __builtin_amdgcn_mfma_f32_16x16x32_f16((a),(b),(c),0,0,0)

__device__ __forceinline__ float tanh_fast(float x){
    float e = __expf(2.f*x);
    return 1.f - 2.f*__builtin_amdgcn_rcpf(e + 1.f);
}

// workgroup barrier WITHOUT vmcnt drain (cross-wave comms are LDS-only)
__device__ __forceinline__ void bar_nodrain(){
    __builtin_amdgcn_sched_barrier(0);
    asm volatile("s_waitcnt lgkmcnt(0)" ::: "memory");
    __builtin_amdgcn_sched_barrier(0);
    __builtin_amdgcn_s_barrier();
    __builtin_amdgcn_sched_barrier(0);
}

__device__ __forceinline__ f16x8 lds_rd8(const _Float16* b, int sB, int row, int colE){
    int off = row*sB + colE*2; off ^= (row&7)<<4;
    return *(const f16x8*)((const char*)b + off);
}
__device__ __forceinline__ void lds_wr1(_Float16* b, int sB, int row, int colE, float v){
    int off = row*sB + colE*2; off ^= (row&7)<<4;
    *(_Float16*)((char*)b + off) = (_Float16)v;
}
// packed 2xf16 write (one ds_write_b32); colE must be even
__device__ __forceinline__ void lds_wr2(_Float16* b, int sB, int row, int colE, float lo, float hi){
    int off = row*sB + colE*2; off ^= (row&7)<<4;
    union { _Float16 h[2]; unsigned u; } pk;
    pk.h[0] = (_Float16)lo; pk.h[1] = (_Float16)hi;
    *(unsigned*)((char*)b + off) = pk.u;
}

// B-frag gather from row-major fp32 W[K][N]: lane holds B[k0+8*(lane>>4)+i][n]
__device__ __forceinline__ f16x8 gbl_bfrag(const float* W, int ldN, int k0, int n){
    f16x8 f;
#pragma unroll
    for(int i=0;i<8;++i) f[i] = (_Float16)W[(size_t)(k0+i)*ldN + n];
    return f;
}
// B-frag gather in the PACKED-h k-order: k_eff(i) = 32q + 4*lg + (i>>1) + 16*(i&1)
__device__ __forceinline__ f16x8 gbl_bfrag_pk(const float* W, int ldN, int q, int lg, int n){
    f16x8 f;
#pragma unroll
    for(int i=0;i<8;++i){
        int k = 32*q + 4*lg + (i>>1) + 16*(i&1);
        f[i] = (_Float16)W[(size_t)k*ldN + n];
    }
    return f;
}

__global__ __launch_bounds__(512, 1) void ode_decoder_kernel(
    const float* __restrict__ z0, const float* __restrict__ times,
    const float* __restrict__ W1, const float* __restrict__ b1,
    const float* __restrict__ W2, const float* __restrict__ b2,
    const float* __restrict__ dW1, const float* __restrict__ db1,
    const float* __restrict__ dW2, const float* __restrict__ db2,
    const float* __restrict__ dW3, const float* __restrict__ db3,
    float* __restrict__ out)
{
    __shared__ _Float16 z_lds[16*LATENT]   __attribute__((aligned(16))); // 4 KB
    __shared__ _Float16 h_lds[16*HIDDEN]   __attribute__((aligned(16))); // 8 KB (packed k-order)
    __shared__ _Float16 epz[2][16*LATENT]  __attribute__((aligned(16))); // 8 KB endpoint z (parity)
    __shared__ _Float16 epf[2][16*LATENT]  __attribute__((aligned(16))); // 8 KB endpoint f
    __shared__ _Float16 h1i[2][64*DECH]    __attribute__((aligned(16))); // 16 KB (parity dbuf)
    __shared__ _Float16 h2i[2][64*DECH]    __attribute__((aligned(16))); // 16 KB
    __shared__ float    tl[TT];

    const int tid  = threadIdx.x;
    const int wv   = tid >> 6;
    const int lane = tid & 63;
    const int lr   = lane & 15;
    const int lg   = lane >> 4;
    const int row0 = 4*lg;
    const int gRow0 = blockIdx.x * 16;
    const bool ct  = (wv < 4);      // chain team: waves 0-3; decode team: waves 4-7
    const int wc   = wv & 3;        // chain wave id
    const int dwv  = wv & 3;        // decode wave id
    const int nsl  = dwv;           // decode n-slice (N=64 in 4x16)

    if(tid < TT) tl[tid] = times[tid];

    // ---------- per-team persistent registers (disjoint liveness) ----------
    f16x8 w1f[4][4], w2f[2][8];                 // chain team
    f32x4 z[2], acc[2];
    float b1v[4], b2v[2];
    f16x8 dw1f[4], dw2f[2], dw3f[2][2];         // decode team
    f32x4 UA = {0,0,0,0}, VA = {0,0,0,0}, UB = {0,0,0,0}, VB = {0,0,0,0};
    float db1v = 0.f, db2v = 0.f, db3v[2] = {0.f,0.f};

    if(ct){
        // chain weights: G1 wave owns N-cols [64wc,64wc+64); G2 owns [32wc,32wc+32) (packed k-order)
#pragma unroll
        for(int t=0;t<4;++t)
#pragma unroll
            for(int q=0;q<4;++q)
                w1f[t][q] = gbl_bfrag(W1, HIDDEN, 32*q+8*lg, 64*wc+16*t+lr);
#pragma unroll
        for(int u=0;u<2;++u)
#pragma unroll
            for(int q=0;q<8;++q)
                w2f[u][q] = gbl_bfrag_pk(W2, LATENT, q, lg, 32*wc+16*u+lr);
#pragma unroll
        for(int t=0;t<4;++t) b1v[t] = b1[64*wc+16*t+lr];
#pragma unroll
        for(int u=0;u<2;++u) b2v[u] = b2[32*wc+16*u+lr];
        // state: lane owns z[row0+r][32wc+16u+lr]
#pragma unroll
        for(int u=0;u<2;++u)
#pragma unroll
            for(int r=0;r<4;++r){
                z[u][r] = z0[(size_t)(gRow0+row0+r)*LATENT + 32*wc+16*u+lr];
                lds_wr1(z_lds, LATENT*2, row0+r, 32*wc+16*u+lr, z[u][r]);
            }
    } else {
        // decoder weights: dW1/dW2 n-slice nsl (N=64); dW3 wave owns cols [32dwv,32dwv+32)
#pragma unroll
        for(int q=0;q<4;++q) dw1f[q] = gbl_bfrag(dW1, DECH, 32*q+8*lg, 16*nsl+lr);
#pragma unroll
        for(int q=0;q<2;++q) dw2f[q] = gbl_bfrag(dW2, DECH, 32*q+8*lg, 16*nsl+lr);
#pragma unroll
        for(int u=0;u<2;++u)
#pragma unroll
            for(int q=0;q<2;++q)
                dw3f[u][q] = gbl_bfrag(dW3, OUTD, 32*q+8*lg, 32*dwv+16*u+lr);
        db1v = db1[16*nsl+lr]; db2v = db2[16*nsl+lr];
#pragma unroll
        for(int u=0;u<2;++u) db3v[u] = db3[32*dwv+16*u+lr];
    }
    bar_nodrain();

    // ---------- chain team bodies (4-wave, R6 layout + R11 packed h) ----------
    auto G1SEG = [&]{
        f16x8 az[4];
#pragma unroll
        for(int q=0;q<4;++q) az[q] = lds_rd8(z_lds, LATENT*2, lr, 32*q+8*lg);
        f32x4 c[4];
#pragma unroll
        for(int t=0;t<4;++t) c[t] = (f32x4){b1v[t],b1v[t],b1v[t],b1v[t]};
#pragma unroll
        for(int q=0;q<4;++q)
#pragma unroll
            for(int t=0;t<4;++t) c[t] = MFMA16(az[q], w1f[t][q], c[t]);
#pragma unroll
        for(int m=0;m<2;++m){
            const int uu = 2*wc+m;
#pragma unroll
            for(int r=0;r<4;++r)
                lds_wr2(h_lds, HIDDEN*2, row0+r, 2*(16*uu+lr),
                        tanh_fast(c[2*m][r]), tanh_fast(c[2*m+1][r]));
        }
    };
    auto G2SEG = [&](f32x4 kk[2]){
        f16x8 ah[8];
#pragma unroll
        for(int q=0;q<8;++q) ah[q] = lds_rd8(h_lds, HIDDEN*2, lr, 32*q+8*lg);
#pragma unroll
        for(int u=0;u<2;++u){
            f32x4 ca = (f32x4){b2v[u],b2v[u],b2v[u],b2v[u]};
            f32x4 cb = (f32x4){0,0,0,0};
#pragma unroll
            for(int q=0;q<4;++q){ ca = MFMA16(ah[q], w2f[u][q], ca); cb = MFMA16(ah[4+q], w2f[u][4+q], cb); }
            kk[u] = ca + cb;
        }
    };
    auto WRZ = [&](f32x4 zs0, f32x4 zs1){
#pragma unroll
        for(int r=0;r<4;++r){
            lds_wr1(z_lds, LATENT*2, row0+r, 32*wc+lr,    zs0[r]);
            lds_wr1(z_lds, LATENT*2, row0+r, 32*wc+16+lr, zs1[r]);
        }
    };
    auto WREP = [&](int par, f32x4 kk[2]){
#pragma unroll
        for(int u=0;u<2;++u)
#pragma unroll
            for(int r=0;r<4;++r){
                lds_wr1(epz[par], LATENT*2, row0+r, 32*wc+16*u+lr, z[u][r]);
                lds_wr1(epf[par], LATENT*2, row0+r, 32*wc+16*u+lr, kk[u][r]);
            }
    };

    // ---------- decode team bodies (4-wave) ----------
    auto UVGEMM = [&](int par){   // UB = ep_z@dW1, VB = ep_f@dW1 (wave's 16-col n-slice)
        f32x4 u = {0,0,0,0}, v = {0,0,0,0};
#pragma unroll
        for(int q=0;q<4;++q){
            u = MFMA16(lds_rd8(epz[par], LATENT*2, lr, 32*q+8*lg), dw1f[q], u);
            v = MFMA16(lds_rd8(epf[par], LATENT*2, lr, 32*q+8*lg), dw1f[q], v);
        }
        UB = u; VB = v;
    };
    // Hermite-combined dG1: h1(p) = relu(a0*UA + a1*VA + a2*UB + a3*VB + db1), all 4 pts of round
    auto CMB = [&](int par, int p0, int jj){
        const float t0 = tl[20*jj];
        const float tB = (jj==NMACRO-1) ? tl[TT-1] : tl[20*jj+20];
        const float hp = tB - t0, rhp = 1.f/hp;
        _Float16* h1 = h1i[par];
#pragma unroll
        for(int pi=0;pi<4;++pi){
            const float th = (tl[p0+pi]-t0)*rhp;
            const float t2 = th*th, t3 = t2*th;
            const float a0 = 2.f*t3-3.f*t2+1.f, a1 = (t3-2.f*t2+th)*hp;
            const float a2 = 3.f*t2-2.f*t3,     a3 = (t3-t2)*hp;
#pragma unroll
            for(int r=0;r<4;++r){
                float v = a0*UA[r] + a1*VA[r] + a2*UB[r] + a3*VB[r] + db1v;
                lds_wr1(h1, DECH*2, 16*pi+row0+r, 16*nsl+lr, fmaxf(v,0.f));
            }
        }
    };
    auto DG2 = [&](int par){
        const _Float16* h1 = h1i[par];
        _Float16* h2 = h2i[par];
#pragma unroll
        for(int mt=0;mt<4;++mt){
            f32x4 c = {db2v,db2v,db2v,db2v};
#pragma unroll
            for(int q=0;q<2;++q) c = MFMA16(lds_rd8(h1, DECH*2, 16*mt+lr, 32*q+8*lg), dw2f[q], c);
#pragma unroll
            for(int r=0;r<4;++r) lds_wr1(h2, DECH*2, 16*mt+row0+r, 16*nsl+lr, fmaxf(c[r],0.f));
        }
    };
    auto DG3 = [&](int par, int p0){
        const _Float16* h2 = h2i[par];
#pragma unroll
        for(int mt=0;mt<4;++mt){
            f16x8 a[2];
#pragma unroll
            for(int q=0;q<2;++q) a[q] = lds_rd8(h2, DECH*2, 16*mt+lr, 32*q+8*lg);
#pragma unroll
            for(int u=0;u<2;++u){
                f32x4 c = {db3v[u],db3v[u],db3v[u],db3v[u]};
#pragma unroll
                for(int q=0;q<2;++q) c = MFMA16(a[q], dw3f[u][q], c);
#pragma unroll
                for(int r=0;r<4;++r)
                    out[(size_t)(gRow0+row0+r)*TT*OUTD + (size_t)(p0+mt)*OUTD + 32*dwv+16*u+lr] = c[r];
            }
        }
    };

    // ---------- main: 5 macro RK4 steps; decode team trails by one interval ----------
#pragma unroll 1
    for(int j=0;j<NMACRO;++j){
        const int  m0 = 20*j;
        const int  m1 = (m0+20 < TT-1) ? m0+20 : TT-1;
        const float hj = tl[m1]-tl[m0];
        const bool dA = (j>=1);
        const bool dD = (j>=2);
        const int  rb = 5*(j-1);
        f32x4 kk[2];

        // s0a
        if(ct) G1SEG(); else if(dD){ DG2((rb-1)&1); DG3((rb-2)&1, 4*(rb-2)); }
        bar_nodrain();
        // s0b
        if(ct){
            G2SEG(kk);
            WREP(j&1, kk);
#pragma unroll
            for(int u=0;u<2;++u) acc[u] = z[u] + kk[u]*(hj*(1.f/6.f));
            WRZ(z[0] + kk[0]*(hj*0.5f), z[1] + kk[1]*(hj*0.5f));
        } else if(dD) DG3((rb-1)&1, 4*(rb-1));
        bar_nodrain();
        // s1a
        if(ct) G1SEG(); else UVGEMM(j&1);
        bar_nodrain();
        // s1b
        if(ct){
            G2SEG(kk);
#pragma unroll
            for(int u=0;u<2;++u) acc[u] += kk[u]*(hj*(1.f/3.f));
            WRZ(z[0] + kk[0]*(hj*0.5f), z[1] + kk[1]*(hj*0.5f));
        } else if(dA) CMB(rb&1, 4*rb, j-1);
        bar_nodrain();
        // s2a
        if(ct) G1SEG(); else if(dA){ CMB((rb+1)&1, 4*(rb+1), j-1); DG2(rb&1); }
        bar_nodrain();
        // s2b
        if(ct){
            G2SEG(kk);
#pragma unroll
            for(int u=0;u<2;++u) acc[u] += kk[u]*(hj*(1.f/3.f));
            WRZ(z[0] + kk[0]*hj, z[1] + kk[1]*hj);
        } else if(dA){ CMB((rb+2)&1, 4*(rb+2), j-1); DG2((rb+1)&1); DG3(rb&1, 4*rb); }
        bar_nodrain();
        // s3a
        if(ct) G1SEG(); else if(dA){ CMB((rb+3)&1, 4*(rb+3), j-1); DG2((rb+2)&1); DG3((rb+1)&1, 4*(rb+1)); }
        bar_nodrain();
        // s3b
        if(ct){
            G2SEG(kk);
#pragma unroll
            for(int u=0;u<2;++u) z[u] = acc[u] + kk[u]*(hj*(1.f/6.f));
            WRZ(z[0], z[1]);
        } else {
            if(dA){ CMB((rb+4)&1, 4*(rb+4), j-1); DG2((rb+3)&1); DG3((rb+2)&1, 4*(rb+2)); }
            UA = UB; VA = VB;   // endpoint j's U/V becomes the "A" side for interval j
        }
        bar_nodrain();
    }

    // ---------- tail: f(z_end) + finish interval 3 spill + decode interval 4 (rounds 20..24) ----------
    {
        f32x4 kk[2];
        // T0a
        if(ct) G1SEG(); else { DG2(19&1); DG3(18&1, 72); }
        bar_nodrain();
        // T0b
        if(ct){ G2SEG(kk); WREP(NMACRO&1, kk); }
        else DG3(19&1, 76);
        bar_nodrain();
        // T1a
        if(!ct) UVGEMM(NMACRO&1);
        bar_nodrain();
        // T1b
        if(!ct) CMB(20&1, 80, 4);
        bar_nodrain();
        // T2a
        if(!ct){ CMB(21&1, 84, 4); DG2(20&1); }
        bar_nodrain();
        // T2b
        if(!ct){ CMB(22&1, 88, 4); DG2(21&1); DG3(20&1, 80); }
        bar_nodrain();
        // T3a
        if(!ct){ CMB(23&1, 92, 4); DG2(22&1); DG3(21&1, 84); }
        bar_nodrain();
        // T3b
        if(!ct){ CMB(24&1, 96, 4); DG2(23&1); DG3(22&1, 88); }
        bar_nodrain();
        // T4a
        if(!ct){ DG2(24&1); DG3(23&1, 92); }
        bar_nodrain();
        // T4b
        if(!ct) DG3(24&1, 96);
    }
}

extern "C" void kernel_launch(void* const* d_in, const int* in_sizes, int n_in,
                              void* d_out, int out_size, void* d_ws, size_t ws_size,
                              hipStream_t stream) {
    ode_decoder_kernel<<<dim3(256), dim3(512), 0, stream>>>(
        (const float*)d_in[0],  (const float*)d_in[1],
        (const float*)d_in[2],  (const float*)d_in[3],
        (const float*)d_in[4],  (const float*)d_in[5],
        (const float*)d_in[6],  (const float*)d_in[7],
        (const float*)d_in[8],  (const float*)d_in[9],
        (const float*)d_in[10], (const float*)d_in[11],
        (float*)d_out);
}

// Round 14
// 144.632 us; speedup vs baseline: 1.0038x; 1.0038x over previous
//
#include <hip/hip_runtime.h>

#define LATENT 128
#define HIDDEN 256
#define OUTD   128
#define TT     100
#define DECH   64
#define NM     5          // RK4 macro-steps of 20 grid intervals (last = 19)
#define NCHAIN 256
#define EPMAGIC 0x5A1EC0DEu

typedef _Float16 f16x8 __attribute__((ext_vector_type(8)));
typedef float    f32x4 __attribute__((ext_vector_type(4)));

#define MFMA16(a,b,c) __builtin_amdgcn_mfma_f32_16x16x32_f16((a),(b),(c),0,0,0)

__device__ __forceinline__ float tanh_fast(float x){
    float e = __expf(2.f*x);
    return 1.f - 2.f*__builtin_amdgcn_rcpf(e + 1.f);
}

// workgroup barrier WITHOUT vmcnt drain (cross-wave comms via LDS only)
__device__ __forceinline__ void bar_nodrain(){
    __builtin_amdgcn_sched_barrier(0);
    asm volatile("s_waitcnt lgkmcnt(0)" ::: "memory");
    __builtin_amdgcn_sched_barrier(0);
    __builtin_amdgcn_s_barrier();
    __builtin_amdgcn_sched_barrier(0);
}

__device__ __forceinline__ f16x8 lds_rd8(const _Float16* b, int sB, int row, int colE){
    int off = row*sB + colE*2; off ^= (row&7)<<4;
    return *(const f16x8*)((const char*)b + off);
}
__device__ __forceinline__ void lds_wr1(_Float16* b, int sB, int row, int colE, float v){
    int off = row*sB + colE*2; off ^= (row&7)<<4;
    *(_Float16*)((char*)b + off) = (_Float16)v;
}
__device__ __forceinline__ void lds_wr2(_Float16* b, int sB, int row, int colE, float lo, float hi){
    int off = row*sB + colE*2; off ^= (row&7)<<4;
    union { _Float16 h[2]; unsigned u; } pk;
    pk.h[0] = (_Float16)lo; pk.h[1] = (_Float16)hi;
    *(unsigned*)((char*)b + off) = pk.u;
}

__device__ __forceinline__ f16x8 gbl_bfrag(const float* W, int ldN, int k0, int n){
    f16x8 f;
#pragma unroll
    for(int i=0;i<8;++i) f[i] = (_Float16)W[(size_t)(k0+i)*ldN + n];
    return f;
}
__device__ __forceinline__ f16x8 gbl_bfrag_pk(const float* W, int ldN, int q, int lg, int n){
    f16x8 f;
#pragma unroll
    for(int i=0;i<8;++i){
        int k = 32*q + 4*lg + (i>>1) + 16*(i&1);
        f[i] = (_Float16)W[(size_t)k*ldN + n];
    }
    return f;
}
__device__ __forceinline__ unsigned pk2f16(float z, float f){
    union{_Float16 h; unsigned short s;} a,b;
    a.h = (_Float16)z; b.h = (_Float16)f;
    return (unsigned)a.s | ((unsigned)b.s<<16);
}

__global__ __launch_bounds__(512, 2) void ode_pc_kernel(
    const float* __restrict__ z0, const float* __restrict__ times,
    const float* __restrict__ W1, const float* __restrict__ b1,
    const float* __restrict__ W2, const float* __restrict__ b2,
    const float* __restrict__ dW1, const float* __restrict__ db1,
    const float* __restrict__ dW2, const float* __restrict__ db2,
    const float* __restrict__ dW3, const float* __restrict__ db3,
    float* __restrict__ out, unsigned* __restrict__ wsu)
{
    __shared__ _Float16 z_lds[16*LATENT]  __attribute__((aligned(16)));
    __shared__ _Float16 h_lds[16*HIDDEN]  __attribute__((aligned(16)));
    __shared__ _Float16 h1i[2][64*DECH]   __attribute__((aligned(16)));
    __shared__ _Float16 h2i[2][64*DECH]   __attribute__((aligned(16)));
    __shared__ float    tl[TT];

    unsigned* epu   = wsu;                                 // [256][6][2048] packed (z|f)
    unsigned* flags = wsu + (size_t)NCHAIN*6*2048;         // [256][6]

    const int tid  = threadIdx.x;
    const int wv   = tid >> 6;
    const int lane = tid & 63;
    const int lr   = lane & 15;
    const int lg   = lane >> 4;
    const int row0 = 4*lg;
    const bool isChain = (blockIdx.x < NCHAIN);
    const int b    = isChain ? blockIdx.x : blockIdx.x - NCHAIN;
    const int gRow0 = b*16;

    if(tid < TT) tl[tid] = times[tid];

    if(isChain){
        // ================= CHAIN (blocks 0..255): pure RK4, 8-wave =================
        f16x8 w1f[2][4];
#pragma unroll
        for(int t=0;t<2;++t)
#pragma unroll
            for(int q=0;q<4;++q)
                w1f[t][q] = gbl_bfrag(W1, HIDDEN, 32*q+8*lg, 32*wv+16*t+lr);
        f16x8 w2f[8];
#pragma unroll
        for(int q=0;q<8;++q)
            w2f[q] = gbl_bfrag_pk(W2, LATENT, q, lg, 16*wv+lr);
        const float b1v0 = b1[32*wv+lr], b1v1 = b1[32*wv+16+lr];
        const float b2v  = b2[16*wv+lr];

        f32x4 z, acc = {0,0,0,0};
#pragma unroll
        for(int r=0;r<4;++r){
            z[r] = z0[(size_t)(gRow0+row0+r)*LATENT + 16*wv + lr];
            lds_wr1(z_lds, LATENT*2, row0+r, 16*wv+lr, z[r]);
        }
        __syncthreads();

        auto G1SEG = [&]{
            f16x8 az[4];
#pragma unroll
            for(int q=0;q<4;++q) az[q] = lds_rd8(z_lds, LATENT*2, lr, 32*q+8*lg);
            f32x4 c0 = {b1v0,b1v0,b1v0,b1v0};
            f32x4 c1 = {b1v1,b1v1,b1v1,b1v1};
#pragma unroll
            for(int q=0;q<4;++q){ c0 = MFMA16(az[q], w1f[0][q], c0); c1 = MFMA16(az[q], w1f[1][q], c1); }
#pragma unroll
            for(int r=0;r<4;++r)
                lds_wr2(h_lds, HIDDEN*2, row0+r, 2*(16*wv+lr), tanh_fast(c0[r]), tanh_fast(c1[r]));
        };
        auto G2SEG = [&]() -> f32x4 {
            f16x8 ah[8];
#pragma unroll
            for(int q=0;q<8;++q) ah[q] = lds_rd8(h_lds, HIDDEN*2, lr, 32*q+8*lg);
            f32x4 ca = {b2v,b2v,b2v,b2v}, cb = {0,0,0,0};
#pragma unroll
            for(int q=0;q<4;++q){ ca = MFMA16(ah[q], w2f[q], ca); cb = MFMA16(ah[4+q], w2f[4+q], cb); }
            return ca + cb;
        };
        auto WRZ = [&](f32x4 zs){
#pragma unroll
            for(int r=0;r<4;++r) lds_wr1(z_lds, LATENT*2, row0+r, 16*wv+lr, zs[r]);
        };
        auto PUB = [&](int j, f32x4 ff){
            unsigned* pe = epu + (size_t)(b*6+j)*2048;
#pragma unroll
            for(int r=0;r<4;++r)
                __hip_atomic_store(&pe[(row0+r)*128 + 16*wv+lr], pk2f16(z[r], ff[r]),
                                   __ATOMIC_RELAXED, __HIP_MEMORY_SCOPE_AGENT);
        };

#pragma unroll 1
        for(int j=0;j<NM;++j){
            const int  m0 = 20*j;
            const int  m1 = (m0+20 < TT-1) ? m0+20 : TT-1;
            const float hj = tl[m1]-tl[m0];

            G1SEG();
            __syncthreads();
            {
                f32x4 k1 = G2SEG();
                PUB(j, k1);
                acc = z + k1*(hj*(1.f/6.f));
                WRZ(z + k1*(hj*0.5f));
            }
            __syncthreads();   // drains vmcnt -> endpoint stores done for all waves
            if(tid==0) __hip_atomic_store(&flags[b*6+j], EPMAGIC, __ATOMIC_RELEASE, __HIP_MEMORY_SCOPE_AGENT);
            G1SEG();
            __syncthreads();
            {
                f32x4 k2 = G2SEG();
                acc += k2*(hj*(1.f/3.f));
                WRZ(z + k2*(hj*0.5f));
            }
            __syncthreads();
            G1SEG();
            __syncthreads();
            {
                f32x4 k3 = G2SEG();
                acc += k3*(hj*(1.f/3.f));
                WRZ(z + k3*hj);
            }
            __syncthreads();
            G1SEG();
            __syncthreads();
            {
                f32x4 k4 = G2SEG();
                z = acc + k4*(hj*(1.f/6.f));
                WRZ(z);
            }
            __syncthreads();
        }
        // tail endpoint NM = (z_end, f(z_end))
        G1SEG();
        __syncthreads();
        {
            f32x4 kt = G2SEG();
            PUB(NM, kt);
        }
        __syncthreads();
        if(tid==0) __hip_atomic_store(&flags[b*6+NM], EPMAGIC, __ATOMIC_RELEASE, __HIP_MEMORY_SCOPE_AGENT);

    } else {
        // ================= DECODE (blocks 256..511): trails chain =================
        const int nsl = wv & 3;
        const int ph  = wv >> 2;
        f16x8 dw1f[4], dw2f[2], dw3f[2];
#pragma unroll
        for(int q=0;q<4;++q) dw1f[q] = gbl_bfrag(dW1, DECH, 32*q+8*lg, 16*nsl+lr);
#pragma unroll
        for(int q=0;q<2;++q) dw2f[q] = gbl_bfrag(dW2, DECH, 32*q+8*lg, 16*nsl+lr);
#pragma unroll
        for(int q=0;q<2;++q) dw3f[q] = gbl_bfrag(dW3, OUTD, 32*q+8*lg, 16*wv+lr);
        const float db1v = db1[16*nsl+lr], db2v = db2[16*nsl+lr];
        const float db3v = db3[16*wv+lr];

#pragma unroll 1
        for(int j=0;j<NM;++j){
            while(__hip_atomic_load(&flags[b*6+j+1], __ATOMIC_ACQUIRE, __HIP_MEMORY_SCOPE_AGENT) != EPMAGIC)
                __builtin_amdgcn_s_sleep(8);
            if(j==0)
                while(__hip_atomic_load(&flags[b*6+0], __ATOMIC_ACQUIRE, __HIP_MEMORY_SCOPE_AGENT) != EPMAGIC)
                    __builtin_amdgcn_s_sleep(8);

            // staged endpoint loads (plain loads after acquire) -> U/V via MFMA
            const unsigned* eA = epu + (size_t)(b*6+j)*2048;
            const unsigned* eB = epu + (size_t)(b*6+j+1)*2048;
            f32x4 UA={0,0,0,0}, VA={0,0,0,0}, UB={0,0,0,0}, VB={0,0,0,0};
#pragma unroll
            for(int q=0;q<4;++q){
                f16x8 zf, ff;
#pragma unroll
                for(int i=0;i<8;++i){
                    unsigned ua = eA[lr*128 + 32*q+8*lg + i];
                    union{unsigned short s; _Float16 h;} t;
                    t.s = (unsigned short)(ua&0xffff); zf[i] = t.h;
                    t.s = (unsigned short)(ua>>16);    ff[i] = t.h;
                }
                UA = MFMA16(zf, dw1f[q], UA);
                VA = MFMA16(ff, dw1f[q], VA);
            }
#pragma unroll
            for(int q=0;q<4;++q){
                f16x8 zf, ff;
#pragma unroll
                for(int i=0;i<8;++i){
                    unsigned ub = eB[lr*128 + 32*q+8*lg + i];
                    union{unsigned short s; _Float16 h;} t;
                    t.s = (unsigned short)(ub&0xffff); zf[i] = t.h;
                    t.s = (unsigned short)(ub>>16);    ff[i] = t.h;
                }
                UB = MFMA16(zf, dw1f[q], UB);
                VB = MFMA16(ff, dw1f[q], VB);
            }
            const float t0 = tl[20*j];
            const float tB = (j==NM-1) ? tl[TT-1] : tl[20*j+20];
            const float hp = tB - t0, rhp = 1.f/hp;

            auto CMB = [&](int r){
                _Float16* h1 = h1i[r&1];
                const int p0 = 20*j + 4*r;
#pragma unroll
                for(int i=0;i<2;++i){
                    const int pi = 2*ph + i;
                    const float th = (tl[p0+pi]-t0)*rhp;
                    const float t2 = th*th, t3 = t2*th;
                    const float a0 = 2.f*t3-3.f*t2+1.f, a1 = (t3-2.f*t2+th)*hp;
                    const float a2 = 3.f*t2-2.f*t3,     a3 = (t3-t2)*hp;
#pragma unroll
                    for(int rr=0;rr<4;++rr){
                        float v = a0*UA[rr] + a1*VA[rr] + a2*UB[rr] + a3*VB[rr] + db1v;
                        lds_wr1(h1, DECH*2, 16*pi+row0+rr, 16*nsl+lr, fmaxf(v,0.f));
                    }
                }
            };
            auto DG2 = [&](int r){
                const _Float16* h1 = h1i[r&1];
                _Float16* h2 = h2i[r&1];
#pragma unroll
                for(int c=0;c<2;++c){ const int mt = 2*ph+c;
                    f32x4 cc = {db2v,db2v,db2v,db2v};
#pragma unroll
                    for(int q=0;q<2;++q) cc = MFMA16(lds_rd8(h1, DECH*2, 16*mt+lr, 32*q+8*lg), dw2f[q], cc);
#pragma unroll
                    for(int rr=0;rr<4;++rr) lds_wr1(h2, DECH*2, 16*mt+row0+rr, 16*nsl+lr, fmaxf(cc[rr],0.f));
                }
            };
            auto DG3 = [&](int r){
                const _Float16* h2 = h2i[r&1];
                const int p0 = 20*j + 4*r;
#pragma unroll
                for(int mt=0;mt<4;++mt){
                    f32x4 cc = {db3v,db3v,db3v,db3v};
#pragma unroll
                    for(int q=0;q<2;++q) cc = MFMA16(lds_rd8(h2, DECH*2, 16*mt+lr, 32*q+8*lg), dw3f[q], cc);
#pragma unroll
                    for(int rr=0;rr<4;++rr)
                        out[(size_t)(gRow0+row0+rr)*TT*OUTD + (size_t)(p0+mt)*OUTD + 16*wv+lr] = cc[rr];
                }
            };

            bar_nodrain();
#pragma unroll 1
            for(int s=0;s<7;++s){
                if(s<5)          CMB(s);
                if(s>=1 && s<6)  DG2(s-1);
                if(s>=2)         DG3(s-2);
                bar_nodrain();
            }
        }
    }
}

extern "C" void kernel_launch(void* const* d_in, const int* in_sizes, int n_in,
                              void* d_out, int out_size, void* d_ws, size_t ws_size,
                              hipStream_t stream) {
    ode_pc_kernel<<<dim3(2*NCHAIN), dim3(512), 0, stream>>>(
        (const float*)d_in[0],  (const float*)d_in[1],
        (const float*)d_in[2],  (const float*)d_in[3],
        (const float*)d_in[4],  (const float*)d_in[5],
        (const float*)d_in[6],  (const float*)d_in[7],
        (const float*)d_in[8],  (const float*)d_in[9],
        (const float*)d_in[10], (const float*)d_in[11],
        (float*)d_out, (unsigned*)d_ws);
}

// Round 15
// 57.373 us; speedup vs baseline: 2.5305x; 2.5209x over previous
//
#include <hip/hip_runtime.h>

#define LATENT 128
#define HIDDEN 256
#define OUTD   128
#define TT     100
#define DECH   64
#define NM     5    // RK4 macro-steps of 20 grid intervals (last = 19)

typedef _Float16 f16x8 __attribute__((ext_vector_type(8)));
typedef float    f32x4 __attribute__((ext_vector_type(4)));

#define MFMA16(a,b,c) __builtin_amdgcn_mfma_f32_16x16x32_f16((a),(b),(c),0,0,0)

__device__ __forceinline__ float tanh_fast(float x){
    float e = __expf(2.f*x);
    return 1.f - 2.f*__builtin_amdgcn_rcpf(e + 1.f);
}

// workgroup barrier WITHOUT vmcnt drain (cross-wave comms are LDS-only)
__device__ __forceinline__ void bar_nodrain(){
    __builtin_amdgcn_sched_barrier(0);
    asm volatile("s_waitcnt lgkmcnt(0)" ::: "memory");
    __builtin_amdgcn_sched_barrier(0);
    __builtin_amdgcn_s_barrier();
    __builtin_amdgcn_sched_barrier(0);
}

__device__ __forceinline__ f16x8 lds_rd8(const _Float16* b, int sB, int row, int colE){
    int off = row*sB + colE*2; off ^= (row&7)<<4;
    return *(const f16x8*)((const char*)b + off);
}
__device__ __forceinline__ void lds_wr1(_Float16* b, int sB, int row, int colE, float v){
    int off = row*sB + colE*2; off ^= (row&7)<<4;
    *(_Float16*)((char*)b + off) = (_Float16)v;
}
__device__ __forceinline__ void lds_wr2(_Float16* b, int sB, int row, int colE, float lo, float hi){
    int off = row*sB + colE*2; off ^= (row&7)<<4;
    union { _Float16 h[2]; unsigned u; } pk;
    pk.h[0] = (_Float16)lo; pk.h[1] = (_Float16)hi;
    *(unsigned*)((char*)b + off) = pk.u;
}

__device__ __forceinline__ f16x8 gbl_bfrag(const float* W, int ldN, int k0, int n){
    f16x8 f;
#pragma unroll
    for(int i=0;i<8;++i) f[i] = (_Float16)W[(size_t)(k0+i)*ldN + n];
    return f;
}
__device__ __forceinline__ f16x8 gbl_bfrag_pk(const float* W, int ldN, int q, int lg, int n){
    f16x8 f;
#pragma unroll
    for(int i=0;i<8;++i){
        int k = 32*q + 4*lg + (i>>1) + 16*(i&1);
        f[i] = (_Float16)W[(size_t)k*ldN + n];
    }
    return f;
}

__global__ __launch_bounds__(1024, 1) void ode_ws_kernel(
    const float* __restrict__ z0, const float* __restrict__ times,
    const float* __restrict__ W1, const float* __restrict__ b1,
    const float* __restrict__ W2, const float* __restrict__ b2,
    const float* __restrict__ dW1, const float* __restrict__ db1,
    const float* __restrict__ dW2, const float* __restrict__ db2,
    const float* __restrict__ dW3, const float* __restrict__ db3,
    float* __restrict__ out)
{
    __shared__ _Float16 z_lds[16*LATENT]   __attribute__((aligned(16))); // 4 KB  (chain)
    __shared__ _Float16 h_lds[16*HIDDEN]   __attribute__((aligned(16))); // 8 KB  (chain)
    __shared__ _Float16 epz[2][16*LATENT]  __attribute__((aligned(16))); // 8 KB  (handoff)
    __shared__ _Float16 epf[2][16*LATENT]  __attribute__((aligned(16))); // 8 KB
    __shared__ _Float16 h1i[2][64*DECH]    __attribute__((aligned(16))); // 16 KB (decode)
    __shared__ _Float16 h2i[2][64*DECH]    __attribute__((aligned(16))); // 16 KB
    __shared__ float    tl[TT];

    const int tid  = threadIdx.x;
    const int wv   = tid >> 6;       // 0..15
    const int lane = tid & 63;
    const int lr   = lane & 15;
    const int lg   = lane >> 4;
    const int row0 = 4*lg;
    const int gRow0 = blockIdx.x * 16;

    if(tid < TT) tl[tid] = times[tid];

    if(wv < 8){
        // ======================= CHAIN TEAM (waves 0-7) =======================
        const int wc = wv;
        f16x8 w1f[2][4];
#pragma unroll
        for(int t=0;t<2;++t)
#pragma unroll
            for(int q=0;q<4;++q)
                w1f[t][q] = gbl_bfrag(W1, HIDDEN, 32*q+8*lg, 32*wc+16*t+lr);
        f16x8 w2f[8];
#pragma unroll
        for(int q=0;q<8;++q)
            w2f[q] = gbl_bfrag_pk(W2, LATENT, q, lg, 16*wc+lr);
        const float b1v0 = b1[32*wc+lr], b1v1 = b1[32*wc+16+lr];
        const float b2v  = b2[16*wc+lr];

        f32x4 z, acc = {0,0,0,0};
#pragma unroll
        for(int r=0;r<4;++r){
            z[r] = z0[(size_t)(gRow0+row0+r)*LATENT + 16*wc + lr];
            lds_wr1(z_lds, LATENT*2, row0+r, 16*wc+lr, z[r]);
        }
        bar_nodrain();                                     // BAR 1 (init)

        auto G1SEG = [&]{
            f16x8 az[4];
#pragma unroll
            for(int q=0;q<4;++q) az[q] = lds_rd8(z_lds, LATENT*2, lr, 32*q+8*lg);
            f32x4 c0 = {b1v0,b1v0,b1v0,b1v0};
            f32x4 c1 = {b1v1,b1v1,b1v1,b1v1};
#pragma unroll
            for(int q=0;q<4;++q){ c0 = MFMA16(az[q], w1f[0][q], c0); c1 = MFMA16(az[q], w1f[1][q], c1); }
#pragma unroll
            for(int r=0;r<4;++r)
                lds_wr2(h_lds, HIDDEN*2, row0+r, 2*(16*wc+lr), tanh_fast(c0[r]), tanh_fast(c1[r]));
        };
        auto G2SEG = [&]() -> f32x4 {
            f16x8 ah[8];
#pragma unroll
            for(int q=0;q<8;++q) ah[q] = lds_rd8(h_lds, HIDDEN*2, lr, 32*q+8*lg);
            f32x4 ca = {b2v,b2v,b2v,b2v}, cb = {0,0,0,0};
#pragma unroll
            for(int q=0;q<4;++q){ ca = MFMA16(ah[q], w2f[q], ca); cb = MFMA16(ah[4+q], w2f[4+q], cb); }
            return ca + cb;
        };
        auto WRZ = [&](f32x4 zs){
#pragma unroll
            for(int r=0;r<4;++r) lds_wr1(z_lds, LATENT*2, row0+r, 16*wc+lr, zs[r]);
        };
        auto WREP = [&](int par, f32x4 ff){
#pragma unroll
            for(int r=0;r<4;++r){
                lds_wr1(epz[par], LATENT*2, row0+r, 16*wc+lr, z[r]);
                lds_wr1(epf[par], LATENT*2, row0+r, 16*wc+lr, ff[r]);
            }
        };

#pragma unroll 1
        for(int j=0;j<NM;++j){
            const int  m0 = 20*j;
            const int  m1 = (m0+20 < TT-1) ? m0+20 : TT-1;
            const float hj = tl[m1]-tl[m0];

            G1SEG();  bar_nodrain();                       // s0a
            {
                f32x4 k1 = G2SEG();
                WREP(j&1, k1);
                acc = z + k1*(hj*(1.f/6.f));
                WRZ(z + k1*(hj*0.5f));
            }
            bar_nodrain();                                 // s0b
            G1SEG();  bar_nodrain();                       // s1a
            {
                f32x4 k2 = G2SEG();
                acc += k2*(hj*(1.f/3.f));
                WRZ(z + k2*(hj*0.5f));
            }
            bar_nodrain();                                 // s1b
            G1SEG();  bar_nodrain();                       // s2a
            {
                f32x4 k3 = G2SEG();
                acc += k3*(hj*(1.f/3.f));
                WRZ(z + k3*hj);
            }
            bar_nodrain();                                 // s2b
            G1SEG();  bar_nodrain();                       // s3a
            {
                f32x4 k4 = G2SEG();
                z = acc + k4*(hj*(1.f/6.f));
                WRZ(z);
            }
            bar_nodrain();                                 // s3b
        }
        // tail: T0, T1 then 7 idle barriers (T2..T8); T9 has no barrier
        G1SEG();  bar_nodrain();                           // T0
        {
            f32x4 kt = G2SEG();
            WREP(NM&1, kt);
        }
        bar_nodrain();                                     // T1
        bar_nodrain(); bar_nodrain(); bar_nodrain();       // T2,T3,T4
        bar_nodrain(); bar_nodrain(); bar_nodrain();       // T5,T6,T7
        bar_nodrain();                                     // T8

    } else {
        // ======================= DECODE TEAM (waves 8-15) =======================
        const int dwv = wv - 8;        // 0..7
        const int nsl = dwv & 3;       // n-slice for CMB/DG2
        const int ph  = dwv >> 2;      // point-half / m-half
        f16x8 dw1f[4], dw2f[2], dw3f[2];
#pragma unroll
        for(int q=0;q<4;++q) dw1f[q] = gbl_bfrag(dW1, DECH, 32*q+8*lg, 16*nsl+lr);
#pragma unroll
        for(int q=0;q<2;++q) dw2f[q] = gbl_bfrag(dW2, DECH, 32*q+8*lg, 16*nsl+lr);
#pragma unroll
        for(int q=0;q<2;++q) dw3f[q] = gbl_bfrag(dW3, OUTD, 32*q+8*lg, 16*dwv+lr);
        const float db1v = db1[16*nsl+lr], db2v = db2[16*nsl+lr];
        const float db3v = db3[16*dwv+lr];

        f32x4 UA={0,0,0,0}, VA={0,0,0,0}, UB={0,0,0,0}, VB={0,0,0,0};

        auto UVGEMM = [&](int par){
            f32x4 u = {0,0,0,0}, v = {0,0,0,0};
#pragma unroll
            for(int q=0;q<4;++q){
                u = MFMA16(lds_rd8(epz[par], LATENT*2, lr, 32*q+8*lg), dw1f[q], u);
                v = MFMA16(lds_rd8(epf[par], LATENT*2, lr, 32*q+8*lg), dw1f[q], v);
            }
            UB = u; VB = v;
        };
        auto CMB = [&](int rid, int p0, float t0, float hp, float rhp){
            _Float16* h1 = h1i[rid&1];
#pragma unroll
            for(int i=0;i<2;++i){
                const int pi = 2*ph + i;
                const float th = (tl[p0+pi]-t0)*rhp;
                const float t2 = th*th, t3 = t2*th;
                const float a0 = 2.f*t3-3.f*t2+1.f, a1 = (t3-2.f*t2+th)*hp;
                const float a2 = 3.f*t2-2.f*t3,     a3 = (t3-t2)*hp;
#pragma unroll
                for(int rr=0;rr<4;++rr){
                    float v = a0*UA[rr] + a1*VA[rr] + a2*UB[rr] + a3*VB[rr] + db1v;
                    lds_wr1(h1, DECH*2, 16*pi+row0+rr, 16*nsl+lr, fmaxf(v,0.f));
                }
            }
        };
        auto DG2 = [&](int rid){
            const _Float16* h1 = h1i[rid&1];
            _Float16* h2 = h2i[rid&1];
#pragma unroll
            for(int c=0;c<2;++c){ const int mt = 2*ph+c;
                f32x4 cc = {db2v,db2v,db2v,db2v};
#pragma unroll
                for(int q=0;q<2;++q) cc = MFMA16(lds_rd8(h1, DECH*2, 16*mt+lr, 32*q+8*lg), dw2f[q], cc);
#pragma unroll
                for(int rr=0;rr<4;++rr) lds_wr1(h2, DECH*2, 16*mt+row0+rr, 16*nsl+lr, fmaxf(cc[rr],0.f));
            }
        };
        auto DG3 = [&](int rid, int p0){
            const _Float16* h2 = h2i[rid&1];
#pragma unroll
            for(int mt=0;mt<4;++mt){
                f32x4 cc = {db3v,db3v,db3v,db3v};
#pragma unroll
                for(int q=0;q<2;++q) cc = MFMA16(lds_rd8(h2, DECH*2, 16*mt+lr, 32*q+8*lg), dw3f[q], cc);
#pragma unroll
                for(int rr=0;rr<4;++rr)
                    out[(size_t)(gRow0+row0+rr)*TT*OUTD + (size_t)(p0+mt)*OUTD + 16*dwv+lr] = cc[rr];
            }
        };

        bar_nodrain();                                     // BAR 1 (init)

#pragma unroll 1
        for(int j=0;j<NM;++j){
            const bool dA = (j>=1);
            const bool dD = (j>=2);
            const int  rb = 5*(j-1);           // first rid of interval j-1
            const int  rs = 5*(j-2);           // first rid of interval j-2 (spillover)
            const int  pb = 20*(j-1);          // first pt of interval j-1
            const float t0  = dA ? tl[20*(j-1)] : 1.f;
            const float hp  = dA ? (tl[20*j]-t0) : 1.f;
            const float rhp = 1.f/hp;

            // s0a
            if(dD){ DG2(rs+4); DG3(rs+3, 20*(j-2)+12); }
            bar_nodrain();
            // s0b
            if(dD){ DG3(rs+4, 20*(j-2)+16); }
            bar_nodrain();
            // s1a
            UVGEMM(j&1);
            bar_nodrain();
            // s1b
            if(dA) CMB(rb, pb, t0, hp, rhp);
            bar_nodrain();
            // s2a
            if(dA){ CMB(rb+1, pb+4, t0, hp, rhp); DG2(rb); }
            bar_nodrain();
            // s2b
            if(dA){ CMB(rb+2, pb+8, t0, hp, rhp); DG2(rb+1); DG3(rb, pb); }
            bar_nodrain();
            // s3a
            if(dA){ CMB(rb+3, pb+12, t0, hp, rhp); DG2(rb+2); DG3(rb+1, pb+4); }
            bar_nodrain();
            // s3b
            if(dA){ CMB(rb+4, pb+16, t0, hp, rhp); DG2(rb+3); DG3(rb+2, pb+8); }
            UA = UB; VA = VB;
            bar_nodrain();
        }
        // tail: interval 3 spillover + interval 4 (rids 20..24, pts 80..99)
        {
            const float t0 = tl[80], hp = tl[TT-1]-t0, rhp = 1.f/hp;
            DG2(19); DG3(18, 72);            bar_nodrain();  // T0
            DG3(19, 76);                     bar_nodrain();  // T1
            UVGEMM(NM&1);                    bar_nodrain();  // T2
            CMB(20, 80, t0, hp, rhp);        bar_nodrain();  // T3
            CMB(21, 84, t0, hp, rhp); DG2(20);               bar_nodrain();  // T4
            CMB(22, 88, t0, hp, rhp); DG2(21); DG3(20, 80);  bar_nodrain();  // T5
            CMB(23, 92, t0, hp, rhp); DG2(22); DG3(21, 84);  bar_nodrain();  // T6
            CMB(24, 96, t0, hp, rhp); DG2(23); DG3(22, 88);  bar_nodrain();  // T7
            DG2(24); DG3(23, 92);            bar_nodrain();  // T8
            DG3(24, 96);                                     // T9 (no barrier)
        }
    }
}

extern "C" void kernel_launch(void* const* d_in, const int* in_sizes, int n_in,
                              void* d_out, int out_size, void* d_ws, size_t ws_size,
                              hipStream_t stream) {
    ode_ws_kernel<<<dim3(256), dim3(1024), 0, stream>>>(
        (const float*)d_in[0],  (const float*)d_in[1],
        (const float*)d_in[2],  (const float*)d_in[3],
        (const float*)d_in[4],  (const float*)d_in[5],
        (const float*)d_in[6],  (const float*)d_in[7],
        (const float*)d_in[8],  (const float*)d_in[9],
        (const float*)d_in[10], (const float*)d_in[11],
        (float*)d_out);
}